// Round 1
// baseline (3293.697 us; speedup 1.0000x reference)
//
#include <hip/hip_runtime.h>
#include <hip/hip_bf16.h>

#define IN_DIM 128
#define OUT_DIM 256
#define KDIM 256            // 2*IN_DIM
#define GEMM_ROWS 16
#define EPS 1e-12f

// ---------------------------------------------------------------------------
// Kernel 1: edge scatter.  work item = (edge e, 4-float chunk c in [0,32))
//   agg[src[e]][c*4 .. c*4+3] += x[dst[e]][c*4 .. c*4+3] * w[e]
//   wsum[src[e]] += w[e]   (chunk 0 only)
// ---------------------------------------------------------------------------
__global__ __launch_bounds__(256) void sage_scatter(
    const float* __restrict__ x,
    const int* __restrict__ src,
    const int* __restrict__ dst,
    const float* __restrict__ ew,
    float* __restrict__ agg,
    float* __restrict__ wsum,
    int E) {
  long long total = (long long)E * 32;
  long long stride = (long long)gridDim.x * blockDim.x;
  for (long long idx = (long long)blockIdx.x * blockDim.x + threadIdx.x;
       idx < total; idx += stride) {
    int e = (int)(idx >> 5);
    int c = (int)(idx & 31);
    int s = src[e];
    int d = dst[e];
    float w = ew[e];
    const float4 xv =
        *reinterpret_cast<const float4*>(x + (size_t)d * IN_DIM + c * 4);
    float* a = agg + (size_t)s * IN_DIM + c * 4;
    atomicAdd(a + 0, xv.x * w);
    atomicAdd(a + 1, xv.y * w);
    atomicAdd(a + 2, xv.z * w);
    atomicAdd(a + 3, xv.w * w);
    if (c == 0) atomicAdd(wsum + s, w);
  }
}

// ---------------------------------------------------------------------------
// Kernel 2: fused  h = [x, agg/max(wsum,eps)];  out = relu(h @ W^T + b)
// Block: 256 threads, computes GEMM_ROWS rows x 256 cols of out.
// Thread j owns output column j for all GEMM_ROWS rows.
// h tile staged in LDS [GEMM_ROWS][256]; W row j read as float4 (L2-hot).
// ---------------------------------------------------------------------------
__global__ __launch_bounds__(256) void sage_gemm(
    const float* __restrict__ x,
    const float* __restrict__ agg,
    const float* __restrict__ wsum,
    const float* __restrict__ W,   // [OUT_DIM][KDIM] row-major
    const float* __restrict__ b,
    float* __restrict__ out,
    int N) {
  __shared__ float h[GEMM_ROWS][KDIM];
  const int tid = threadIdx.x;
  const int i0 = blockIdx.x * GEMM_ROWS;

  // stage h tile (coalesced: consecutive tid -> consecutive k)
  for (int idx = tid; idx < GEMM_ROWS * KDIM; idx += 256) {
    int r = idx >> 8;        // row within tile
    int k = idx & 255;       // column in concat space
    int row = i0 + r;
    float v = 0.f;
    if (row < N) {
      if (k < IN_DIM) {
        v = x[(size_t)row * IN_DIM + k];
      } else {
        float ws = wsum[row];
        v = agg[(size_t)row * IN_DIM + (k - IN_DIM)] / fmaxf(ws, EPS);
      }
    }
    h[r][k] = v;
  }
  __syncthreads();

  const int j = tid;  // output column
  const float* __restrict__ Wj = W + (size_t)j * KDIM;
  float acc[GEMM_ROWS];
#pragma unroll
  for (int r = 0; r < GEMM_ROWS; ++r) acc[r] = 0.f;

  for (int k = 0; k < KDIM; k += 4) {
    const float4 wv = *reinterpret_cast<const float4*>(Wj + k);
#pragma unroll
    for (int r = 0; r < GEMM_ROWS; ++r) {
      const float4 hv = *reinterpret_cast<const float4*>(&h[r][k]);
      acc[r] += hv.x * wv.x + hv.y * wv.y + hv.z * wv.z + hv.w * wv.w;
    }
  }

  const float bj = b[j];
#pragma unroll
  for (int r = 0; r < GEMM_ROWS; ++r) {
    int row = i0 + r;
    if (row < N) {
      out[(size_t)row * OUT_DIM + j] = fmaxf(acc[r] + bj, 0.f);
    }
  }
}

extern "C" void kernel_launch(void* const* d_in, const int* in_sizes, int n_in,
                              void* d_out, int out_size, void* d_ws, size_t ws_size,
                              hipStream_t stream) {
  const float* x  = (const float*)d_in[0];
  const int*   ei = (const int*)d_in[1];     // [2][E]
  const float* ew = (const float*)d_in[2];   // [E]
  const float* W  = (const float*)d_in[3];   // [OUT_DIM][KDIM]
  const float* b  = (const float*)d_in[4];   // [OUT_DIM]
  float* out = (float*)d_out;

  const int N = in_sizes[0] / IN_DIM;        // 100000
  const int E = in_sizes[2];                 // 1600000
  const int* src = ei;
  const int* dst = ei + E;

  float* agg  = (float*)d_ws;                // [N][IN_DIM]
  float* wsum = agg + (size_t)N * IN_DIM;    // [N]

  // zero the accumulators (ws is re-poisoned to 0xAA before every call)
  hipMemsetAsync(d_ws, 0, ((size_t)N * IN_DIM + N) * sizeof(float), stream);

  // scatter
  {
    int blocks = 4096;
    sage_scatter<<<blocks, 256, 0, stream>>>(x, src, dst, ew, agg, wsum, E);
  }

  // fused normalize + GEMM + bias + relu
  {
    int blocks = (N + GEMM_ROWS - 1) / GEMM_ROWS;
    sage_gemm<<<blocks, 256, 0, stream>>>(x, agg, wsum, W, b, out, N);
  }
}

// Round 2
// 832.162 us; speedup vs baseline: 3.9580x; 3.9580x over previous
//
#include <hip/hip_runtime.h>
#include <hip/hip_bf16.h>

#define IN_DIM 128
#define OUT_DIM 256
#define KDIM 256            // 2*IN_DIM
#define GEMM_ROWS 16
#define EPS 1e-12f

// ---------------------------------------------------------------------------
// Phase 1: histogram of edge sources.  counts[src[e]]++  (int atomics, cheap)
// ---------------------------------------------------------------------------
__global__ __launch_bounds__(256) void sage_hist(
    const int* __restrict__ src, int* __restrict__ counts, int E) {
  int stride = gridDim.x * blockDim.x;
  for (int e = blockIdx.x * blockDim.x + threadIdx.x; e < E; e += stride)
    atomicAdd(&counts[src[e]], 1);
}

// ---------------------------------------------------------------------------
// Phase 2: bucket offset assignment. We do NOT need a sequential prefix sum —
// any disjoint contiguous placement works. Wave-level exclusive scan of
// counts, one atomicAdd on a global cursor per wave (1563 atomics total).
// ---------------------------------------------------------------------------
__global__ __launch_bounds__(256) void sage_offsets(
    const int* __restrict__ counts,
    int* __restrict__ offsets,
    int* __restrict__ cursor,
    int* __restrict__ gcur, int N) {
  const int i = blockIdx.x * blockDim.x + threadIdx.x;
  const int lane = threadIdx.x & 63;
  int c = (i < N) ? counts[i] : 0;
  int incl = c;
#pragma unroll
  for (int d = 1; d < 64; d <<= 1) {
    int t = __shfl_up(incl, d, 64);
    if (lane >= d) incl += t;
  }
  const int total = __shfl(incl, 63, 64);
  int base = 0;
  if (lane == 63) base = atomicAdd(gcur, total);
  base = __shfl(base, 63, 64);
  const int off = base + incl - c;
  if (i < N) {
    offsets[i] = off;
    cursor[i] = off;
  }
}

// ---------------------------------------------------------------------------
// Phase 3: reorder edges into per-source buckets (int atomics on cursors).
// ---------------------------------------------------------------------------
__global__ __launch_bounds__(256) void sage_reorder(
    const int* __restrict__ src, const int* __restrict__ dst,
    const float* __restrict__ ew,
    int* __restrict__ cursor, int* __restrict__ bdst, float* __restrict__ bw,
    int E) {
  int stride = gridDim.x * blockDim.x;
  for (int e = blockIdx.x * blockDim.x + threadIdx.x; e < E; e += stride) {
    int s = src[e];
    int pos = atomicAdd(&cursor[s], 1);
    bdst[pos] = dst[e];
    bw[pos] = ew[e];
  }
}

// ---------------------------------------------------------------------------
// Phase 4: aggregate. One wave per node; lane holds features [2*lane, 2*lane+1].
// Gathers x[d] as float2 (512B/wave, coalesced), accumulates in registers,
// normalizes, writes neigh exactly once. No float atomics anywhere.
// ---------------------------------------------------------------------------
__global__ __launch_bounds__(256) void sage_aggregate(
    const float* __restrict__ x,
    const int* __restrict__ offsets,
    const int* __restrict__ counts,
    const int* __restrict__ bdst,
    const float* __restrict__ bw,
    float* __restrict__ neigh, int N) {
  const int lane = threadIdx.x & 63;
  const int node = blockIdx.x * 4 + (threadIdx.x >> 6);
  if (node >= N) return;
  const int start = offsets[node];
  const int cnt = counts[node];
  float ax = 0.f, ay = 0.f, ws = 0.f;
  int j = 0;
  for (; j + 4 <= cnt; j += 4) {
    int d0 = bdst[start + j + 0];
    int d1 = bdst[start + j + 1];
    int d2 = bdst[start + j + 2];
    int d3 = bdst[start + j + 3];
    float w0 = bw[start + j + 0];
    float w1 = bw[start + j + 1];
    float w2 = bw[start + j + 2];
    float w3 = bw[start + j + 3];
    const float2 v0 = *reinterpret_cast<const float2*>(x + (size_t)d0 * IN_DIM + lane * 2);
    const float2 v1 = *reinterpret_cast<const float2*>(x + (size_t)d1 * IN_DIM + lane * 2);
    const float2 v2 = *reinterpret_cast<const float2*>(x + (size_t)d2 * IN_DIM + lane * 2);
    const float2 v3 = *reinterpret_cast<const float2*>(x + (size_t)d3 * IN_DIM + lane * 2);
    ax += v0.x * w0 + v1.x * w1 + v2.x * w2 + v3.x * w3;
    ay += v0.y * w0 + v1.y * w1 + v2.y * w2 + v3.y * w3;
    ws += w0 + w1 + w2 + w3;
  }
  for (; j < cnt; ++j) {
    int d = bdst[start + j];
    float w = bw[start + j];
    const float2 v = *reinterpret_cast<const float2*>(x + (size_t)d * IN_DIM + lane * 2);
    ax += v.x * w;
    ay += v.y * w;
    ws += w;
  }
  const float m = fmaxf(ws, EPS);
  float2 r;
  r.x = ax / m;
  r.y = ay / m;
  *reinterpret_cast<float2*>(neigh + (size_t)node * IN_DIM + lane * 2) = r;
}

// ---------------------------------------------------------------------------
// Phase 5: fused  h = [x, neigh];  out = relu(h @ W^T + b)
// (unchanged from round 1 except neigh is pre-normalized)
// ---------------------------------------------------------------------------
__global__ __launch_bounds__(256) void sage_gemm(
    const float* __restrict__ x,
    const float* __restrict__ neigh,
    const float* __restrict__ W,   // [OUT_DIM][KDIM] row-major
    const float* __restrict__ b,
    float* __restrict__ out,
    int N) {
  __shared__ float h[GEMM_ROWS][KDIM];
  const int tid = threadIdx.x;
  const int i0 = blockIdx.x * GEMM_ROWS;

  for (int idx = tid; idx < GEMM_ROWS * KDIM; idx += 256) {
    int r = idx >> 8;
    int k = idx & 255;
    int row = i0 + r;
    float v = 0.f;
    if (row < N) {
      v = (k < IN_DIM) ? x[(size_t)row * IN_DIM + k]
                       : neigh[(size_t)row * IN_DIM + (k - IN_DIM)];
    }
    h[r][k] = v;
  }
  __syncthreads();

  const int j = tid;
  const float* __restrict__ Wj = W + (size_t)j * KDIM;
  float acc[GEMM_ROWS];
#pragma unroll
  for (int r = 0; r < GEMM_ROWS; ++r) acc[r] = 0.f;

  for (int k = 0; k < KDIM; k += 4) {
    const float4 wv = *reinterpret_cast<const float4*>(Wj + k);
#pragma unroll
    for (int r = 0; r < GEMM_ROWS; ++r) {
      const float4 hv = *reinterpret_cast<const float4*>(&h[r][k]);
      acc[r] += hv.x * wv.x + hv.y * wv.y + hv.z * wv.z + hv.w * wv.w;
    }
  }

  const float bj = b[j];
#pragma unroll
  for (int r = 0; r < GEMM_ROWS; ++r) {
    int row = i0 + r;
    if (row < N) {
      out[(size_t)row * OUT_DIM + j] = fmaxf(acc[r] + bj, 0.f);
    }
  }
}

extern "C" void kernel_launch(void* const* d_in, const int* in_sizes, int n_in,
                              void* d_out, int out_size, void* d_ws, size_t ws_size,
                              hipStream_t stream) {
  const float* x  = (const float*)d_in[0];
  const int*   ei = (const int*)d_in[1];     // [2][E] (int64 narrowed to int32 by harness)
  const float* ew = (const float*)d_in[2];   // [E]
  const float* W  = (const float*)d_in[3];   // [OUT_DIM][KDIM]
  const float* b  = (const float*)d_in[4];   // [OUT_DIM]
  float* out = (float*)d_out;

  const int N = in_sizes[0] / IN_DIM;        // 100000
  const int E = in_sizes[2];                 // 1600000
  const int* src = ei;
  const int* dst = ei + E;

  // workspace layout (all 4-byte elems):
  //   neigh[N*128] | counts[N] | offsets[N] | cursor[N] | gcur[16] | bdst[E] | bw[E]
  float* neigh  = (float*)d_ws;
  int* counts   = (int*)(neigh + (size_t)N * IN_DIM);
  int* offsets  = counts + N;
  int* cursor   = offsets + N;
  int* gcur     = cursor + N;
  int* bdst     = gcur + 16;
  float* bwt    = (float*)(bdst + E);

  // zero counts + gcur (offsets/cursor are fully written by sage_offsets)
  hipMemsetAsync(counts, 0, (size_t)N * sizeof(int), stream);
  hipMemsetAsync(gcur, 0, 16 * sizeof(int), stream);

  sage_hist<<<2048, 256, 0, stream>>>(src, counts, E);
  sage_offsets<<<(N + 255) / 256, 256, 0, stream>>>(counts, offsets, cursor, gcur, N);
  sage_reorder<<<2048, 256, 0, stream>>>(src, dst, ew, cursor, bdst, bwt, E);
  sage_aggregate<<<(N + 3) / 4, 256, 0, stream>>>(x, offsets, counts, bdst, bwt, neigh, N);
  sage_gemm<<<(N + GEMM_ROWS - 1) / GEMM_ROWS, 256, 0, stream>>>(x, neigh, W, b, out, N);
}

// Round 3
// 562.146 us; speedup vs baseline: 5.8592x; 1.4803x over previous
//
#include <hip/hip_runtime.h>
#include <hip/hip_bf16.h>

#define IN_DIM 128
#define OUT_DIM 256
#define KDIM 256            // 2*IN_DIM
#define EPS 1e-12f

typedef __attribute__((ext_vector_type(8))) short short8;   // 8 bf16 = 4 VGPR
typedef __attribute__((ext_vector_type(4))) float f32x4;

static __device__ __forceinline__ unsigned short f2bf(float f) {
  __hip_bfloat16 h = __float2bfloat16(f);   // RNE
  return *reinterpret_cast<unsigned short*>(&h);
}

// ---------------------------------------------------------------------------
// Convert x (f32 [N][128]) into cols 0..127 of hb (bf16 [Mpad][256]).
// ---------------------------------------------------------------------------
__global__ __launch_bounds__(256) void cvt_x(
    const float* __restrict__ x, unsigned short* __restrict__ hb, int N) {
  const int total = N * 32;                 // N*128/4
  const int stride = gridDim.x * blockDim.x;
  for (int idx = blockIdx.x * blockDim.x + threadIdx.x; idx < total; idx += stride) {
    const int row = idx >> 5;
    const int c4 = (idx & 31) * 4;
    const float4 v = *reinterpret_cast<const float4*>(x + (size_t)row * IN_DIM + c4);
    ushort4 o;
    o.x = f2bf(v.x); o.y = f2bf(v.y); o.z = f2bf(v.z); o.w = f2bf(v.w);
    *reinterpret_cast<ushort4*>(hb + (size_t)row * KDIM + c4) = o;
  }
}

// ---------------------------------------------------------------------------
// Convert W (f32 [256][256]) -> Wb (bf16, same layout).
// ---------------------------------------------------------------------------
__global__ __launch_bounds__(256) void cvt_w(
    const float* __restrict__ W, unsigned short* __restrict__ Wb) {
  const int idx = blockIdx.x * blockDim.x + threadIdx.x;   // 16384 = 65536/4
  const int base = idx * 4;
  const float4 v = *reinterpret_cast<const float4*>(W + base);
  ushort4 o;
  o.x = f2bf(v.x); o.y = f2bf(v.y); o.z = f2bf(v.z); o.w = f2bf(v.w);
  *reinterpret_cast<ushort4*>(Wb + base) = o;
}

// ---------------------------------------------------------------------------
// Phase 1: histogram of edge sources.
// ---------------------------------------------------------------------------
__global__ __launch_bounds__(256) void sage_hist(
    const int* __restrict__ src, int* __restrict__ counts, int E) {
  int stride = gridDim.x * blockDim.x;
  for (int e = blockIdx.x * blockDim.x + threadIdx.x; e < E; e += stride)
    atomicAdd(&counts[src[e]], 1);
}

// ---------------------------------------------------------------------------
// Phase 2: bucket offsets (wave scan + one global atomic per wave).
// ---------------------------------------------------------------------------
__global__ __launch_bounds__(256) void sage_offsets(
    const int* __restrict__ counts,
    int* __restrict__ offsets,
    int* __restrict__ cursor,
    int* __restrict__ gcur, int N) {
  const int i = blockIdx.x * blockDim.x + threadIdx.x;
  const int lane = threadIdx.x & 63;
  int c = (i < N) ? counts[i] : 0;
  int incl = c;
#pragma unroll
  for (int d = 1; d < 64; d <<= 1) {
    int t = __shfl_up(incl, d, 64);
    if (lane >= d) incl += t;
  }
  const int total = __shfl(incl, 63, 64);
  int base = 0;
  if (lane == 63) base = atomicAdd(gcur, total);
  base = __shfl(base, 63, 64);
  const int off = base + incl - c;
  if (i < N) {
    offsets[i] = off;
    cursor[i] = off;
  }
}

// ---------------------------------------------------------------------------
// Phase 3: reorder edges into buckets; pack (dst, weight_bits) as int2.
// ---------------------------------------------------------------------------
__global__ __launch_bounds__(256) void sage_reorder(
    const int* __restrict__ src, const int* __restrict__ dst,
    const float* __restrict__ ew,
    int* __restrict__ cursor, int2* __restrict__ bpack, int E) {
  int stride = gridDim.x * blockDim.x;
  for (int e = blockIdx.x * blockDim.x + threadIdx.x; e < E; e += stride) {
    int s = src[e];
    int pos = atomicAdd(&cursor[s], 1);
    int2 p;
    p.x = dst[e];
    p.y = __float_as_int(ew[e]);
    bpack[pos] = p;
  }
}

// ---------------------------------------------------------------------------
// Phase 4: aggregate. One wave per node; lane holds features [2*lane,2*lane+1].
// Gathers bf16 pairs (4B/lane) from hb's x-half, accumulates f32, writes the
// normalized result as bf16 into hb's neigh-half.
// ---------------------------------------------------------------------------
__global__ __launch_bounds__(256) void sage_aggregate(
    unsigned short* __restrict__ hb,
    const int* __restrict__ offsets,
    const int* __restrict__ counts,
    const int2* __restrict__ bpack, int N) {
  const int lane = threadIdx.x & 63;
  const int node = blockIdx.x * 4 + (threadIdx.x >> 6);
  if (node >= N) return;
  const int start = offsets[node];
  const int cnt = counts[node];
  float ax = 0.f, ay = 0.f, ws = 0.f;
  int j = 0;
  for (; j + 4 <= cnt; j += 4) {
    int2 p0 = bpack[start + j + 0];
    int2 p1 = bpack[start + j + 1];
    int2 p2 = bpack[start + j + 2];
    int2 p3 = bpack[start + j + 3];
    unsigned v0 = *reinterpret_cast<const unsigned*>(hb + (size_t)p0.x * KDIM + lane * 2);
    unsigned v1 = *reinterpret_cast<const unsigned*>(hb + (size_t)p1.x * KDIM + lane * 2);
    unsigned v2 = *reinterpret_cast<const unsigned*>(hb + (size_t)p2.x * KDIM + lane * 2);
    unsigned v3 = *reinterpret_cast<const unsigned*>(hb + (size_t)p3.x * KDIM + lane * 2);
    float w0 = __int_as_float(p0.y), w1 = __int_as_float(p1.y);
    float w2 = __int_as_float(p2.y), w3 = __int_as_float(p3.y);
    ax += __uint_as_float((v0 & 0xffffu) << 16) * w0 + __uint_as_float((v1 & 0xffffu) << 16) * w1
        + __uint_as_float((v2 & 0xffffu) << 16) * w2 + __uint_as_float((v3 & 0xffffu) << 16) * w3;
    ay += __uint_as_float(v0 & 0xffff0000u) * w0 + __uint_as_float(v1 & 0xffff0000u) * w1
        + __uint_as_float(v2 & 0xffff0000u) * w2 + __uint_as_float(v3 & 0xffff0000u) * w3;
    ws += w0 + w1 + w2 + w3;
  }
  for (; j < cnt; ++j) {
    int2 p = bpack[start + j];
    unsigned v = *reinterpret_cast<const unsigned*>(hb + (size_t)p.x * KDIM + lane * 2);
    float w = __int_as_float(p.y);
    ax += __uint_as_float((v & 0xffffu) << 16) * w;
    ay += __uint_as_float(v & 0xffff0000u) * w;
    ws += w;
  }
  const float m = fmaxf(ws, EPS);
  unsigned o = (unsigned)f2bf(ax / m) | ((unsigned)f2bf(ay / m) << 16);
  *reinterpret_cast<unsigned*>(hb + (size_t)node * KDIM + IN_DIM + lane * 2) = o;
}

// ---------------------------------------------------------------------------
// Phase 5: MFMA GEMM. out = relu(hb_bf16 @ Wb^T + b), fp32 out.
// Block = 4 waves; wave = 32 rows x 256 cols; acc[2][16] f32x4.
// A-frag: 16B contiguous from hb row. B-frag: 16B contiguous from Wb row
// (L2-resident, 128KB). mfma_f32_16x16x32_bf16; C/D: col=lane&15,
// row=(lane>>4)*4+reg  [learn_hip m89].
// ---------------------------------------------------------------------------
__global__ __launch_bounds__(256) void sage_gemm_mfma(
    const unsigned short* __restrict__ hb,
    const unsigned short* __restrict__ Wb,
    const float* __restrict__ bias,
    float* __restrict__ out, int N) {
  const int lane = threadIdx.x & 63;
  const int wave = threadIdx.x >> 6;
  const int row0 = blockIdx.x * 128 + wave * 32;
  const int kc = (lane >> 4) * 8;

  f32x4 acc[2][16];
#pragma unroll
  for (int i = 0; i < 2; ++i)
#pragma unroll
    for (int j = 0; j < 16; ++j) acc[i][j] = (f32x4){0.f, 0.f, 0.f, 0.f};

  const unsigned short* arow0 = hb + (size_t)(row0 + (lane & 15)) * KDIM + kc;
  const unsigned short* arow1 = arow0 + 16 * KDIM;
  const unsigned short* wrow = Wb + (size_t)(lane & 15) * KDIM + kc;

#pragma unroll 1
  for (int kk = 0; kk < 8; ++kk) {
    const short8 a0 = *reinterpret_cast<const short8*>(arow0 + kk * 32);
    const short8 a1 = *reinterpret_cast<const short8*>(arow1 + kk * 32);
#pragma unroll
    for (int ct = 0; ct < 16; ++ct) {
      const short8 bf = *reinterpret_cast<const short8*>(wrow + (size_t)ct * 16 * KDIM + kk * 32);
      acc[0][ct] = __builtin_amdgcn_mfma_f32_16x16x32_bf16(a0, bf, acc[0][ct], 0, 0, 0);
      acc[1][ct] = __builtin_amdgcn_mfma_f32_16x16x32_bf16(a1, bf, acc[1][ct], 0, 0, 0);
    }
  }

  const int col = lane & 15;
  const int rquad = (lane >> 4) * 4;
#pragma unroll
  for (int ct = 0; ct < 16; ++ct) {
    const int j = ct * 16 + col;
    const float bj = bias[j];
#pragma unroll
    for (int rt = 0; rt < 2; ++rt) {
      const int rbase = row0 + rt * 16 + rquad;
      const f32x4 a = acc[rt][ct];
#pragma unroll
      for (int r = 0; r < 4; ++r) {
        const int row = rbase + r;
        if (row < N) out[(size_t)row * OUT_DIM + j] = fmaxf(a[r] + bj, 0.f);
      }
    }
  }
}

extern "C" void kernel_launch(void* const* d_in, const int* in_sizes, int n_in,
                              void* d_out, int out_size, void* d_ws, size_t ws_size,
                              hipStream_t stream) {
  const float* x  = (const float*)d_in[0];
  const int*   ei = (const int*)d_in[1];     // [2][E]
  const float* ew = (const float*)d_in[2];   // [E]
  const float* W  = (const float*)d_in[3];   // [OUT_DIM][KDIM]
  const float* b  = (const float*)d_in[4];   // [OUT_DIM]
  float* out = (float*)d_out;

  const int N = in_sizes[0] / IN_DIM;        // 100000
  const int E = in_sizes[2];                 // 1600000
  const int* src = ei;
  const int* dst = ei + E;

  const int gemm_blocks = (N + 127) / 128;
  const int Mpad = gemm_blocks * 128;        // hb rows (tail reads poison, rows>=N never stored)

  // ws layout:
  //   hb[Mpad][256] bf16 | Wb[256][256] bf16 | counts[N] | offsets[N] |
  //   cursor[N] | gcur[16] | bpack[E] int2
  unsigned short* hb = (unsigned short*)d_ws;
  unsigned short* Wb = hb + (size_t)Mpad * KDIM;
  int* counts  = (int*)(Wb + OUT_DIM * KDIM);
  int* offsets = counts + N;
  int* cursor  = offsets + N;
  int* gcur    = cursor + N;
  int2* bpack  = (int2*)(gcur + 16);

  hipMemsetAsync(counts, 0, (size_t)N * sizeof(int), stream);
  hipMemsetAsync(gcur, 0, 16 * sizeof(int), stream);

  cvt_w<<<(OUT_DIM * KDIM / 4 + 255) / 256, 256, 0, stream>>>(W, Wb);
  cvt_x<<<2048, 256, 0, stream>>>(x, hb, N);
  sage_hist<<<2048, 256, 0, stream>>>(src, counts, E);
  sage_offsets<<<(N + 255) / 256, 256, 0, stream>>>(counts, offsets, cursor, gcur, N);
  sage_reorder<<<2048, 256, 0, stream>>>(src, dst, ew, cursor, bpack, E);
  sage_aggregate<<<(N + 3) / 4, 256, 0, stream>>>(hb, offsets, counts, bpack, N);
  sage_gemm_mfma<<<gemm_blocks, 256, 0, stream>>>(hb, Wb, b, out, N);
}